// Round 4
// baseline (158.888 us; speedup 1.0000x reference)
//
#include <hip/hip_runtime.h>

// SE(3) exp + point transform — persistent, coalesced, barrier-free.
// 1 block per (b,t): 1792 blocks = exactly 7/CU, 4 waves/block = 28 waves/CU,
// single block generation (no relaunch). Each wave owns a private 3 KB LDS
// tile; global access is lane-contiguous float4 both directions. Intra-wave
// LDS exchange is ordered by explicit compiler fences + lgkmcnt(0) (hardware
// executes same-wave DS ops in order; the fence stops compiler reordering —
// the R3 bug). Next iteration's global loads are issued before the compute
// phase so ~400ns of HBM latency overlaps compute + stage-out.

#define LDS_FENCE() asm volatile("s_waitcnt lgkmcnt(0)" ::: "memory")

__global__ __launch_bounds__(256) void se3_apply_kernel(
    const float* __restrict__ X,      // (BT, N, 3) flattened
    const float* __restrict__ dofs,   // (BT, 6)
    float* __restrict__ out,
    int n3)                            // floats per (b,t) = N*3
{
    __shared__ float lds[3072];        // 4 waves x 768 floats (3 KB each)

    const int bt   = blockIdx.x;
    const int lane = threadIdx.x & 63;
    const int w    = threadIdx.x >> 6;

    // ---- SE(3) exponential (uniform per block) ----
    const float* d = dofs + bt * 6;
    const float tx = d[0], ty = d[1], tz = d[2];
    const float wx = d[3], wy = d[4], wz = d[5];

    const float nrm2  = wx * wx + wy * wy + wz * wz;
    const float th2   = fmaxf(nrm2, 1e-4f);      // jnp.clip(nrms, 1e-4)
    const float theta = sqrtf(th2);
    const float st = sinf(theta);
    const float ct = cosf(theta);
    const float f1 = st / theta;
    const float f2 = (1.0f - ct) / th2;
    const float f3 = (theta - st) / (th2 * theta);

    const float xx = wx * wx, yy = wy * wy, zz = wz * wz;
    const float xy = wx * wy, xz = wx * wz, yz = wy * wz;

    const float R00 = 1.0f - f2 * (yy + zz);
    const float R01 = f2 * xy - f1 * wz;
    const float R02 = f2 * xz + f1 * wy;
    const float R10 = f2 * xy + f1 * wz;
    const float R11 = 1.0f - f2 * (xx + zz);
    const float R12 = f2 * yz - f1 * wx;
    const float R20 = f2 * xz - f1 * wy;
    const float R21 = f2 * yz + f1 * wx;
    const float R22 = 1.0f - f2 * (xx + yy);

    const float V00 = 1.0f - f3 * (yy + zz);
    const float V01 = f3 * xy - f2 * wz;
    const float V02 = f3 * xz + f2 * wy;
    const float V10 = f3 * xy + f2 * wz;
    const float V11 = 1.0f - f3 * (xx + zz);
    const float V12 = f3 * yz - f2 * wx;
    const float V20 = f3 * xz - f2 * wy;
    const float V21 = f3 * yz + f2 * wx;
    const float V22 = 1.0f - f3 * (xx + yy);

    const float Tx = V00 * tx + V01 * ty + V02 * tz;
    const float Ty = V10 * tx + V11 * ty + V12 * tz;
    const float Tz = V20 * tx + V21 * ty + V22 * tz;

    const long long btBase = (long long)bt * (long long)n3;
    float* const wlds   = lds + w * 768;         // this wave's private tile
    float4* const wlds4 = (float4*)wlds;

    const int nChunks = n3 / 768;                // 16 for N=4096

    // ---- preload chunk w ----
    float4 v0, v1, v2;
    {
        const float4* __restrict__ g4 = (const float4*)(X + btBase + (long long)w * 768);
        v0 = g4[lane];
        v1 = g4[lane + 64];
        v2 = g4[lane + 128];
    }

    for (int c = w; c < nChunks; c += 4) {
        const long long base = btBase + (long long)c * 768;
        float4* __restrict__ o4 = (float4*)(out + base);

        // stage-in (ds_write waits on this chunk's vmcnt via data dependency)
        wlds4[lane]       = v0;
        wlds4[lane + 64]  = v1;
        wlds4[lane + 128] = v2;
        LDS_FENCE();                             // writes visible before reads

        // prefetch next chunk: overlap HBM latency with compute + stage-out
        const int cn = c + 4;
        if (cn < nChunks) {
            const float4* __restrict__ gn = (const float4*)(X + btBase + (long long)cn * 768);
            v0 = gn[lane];
            v1 = gn[lane + 64];
            v2 = gn[lane + 128];
        }

        // compute in-place: 4 points/lane, stride 64 points (bank-conflict-free)
#pragma unroll
        for (int j = 0; j < 4; ++j) {
            const int p = 3 * (lane + 64 * j);
            const float px = wlds[p + 0];
            const float py = wlds[p + 1];
            const float pz = wlds[p + 2];
            wlds[p + 0] = fmaf(R00, px, fmaf(R01, py, fmaf(R02, pz, Tx)));
            wlds[p + 1] = fmaf(R10, px, fmaf(R11, py, fmaf(R12, pz, Ty)));
            wlds[p + 2] = fmaf(R20, px, fmaf(R21, py, fmaf(R22, pz, Tz)));
        }
        LDS_FENCE();                             // compute visible before stage-out

        // stage-out: lane-contiguous float4 stores
        o4[lane]       = wlds4[lane];
        o4[lane + 64]  = wlds4[lane + 64];
        o4[lane + 128] = wlds4[lane + 128];
        LDS_FENCE();                             // WAR: reads done before next stage-in
    }

    // ---- tail (n3 % 768; zero for N=4096) ----
    const int tailF = n3 - nChunks * 768;
    if (tailF > 0 && w == 0) {
        const int tailPts = tailF / 3;
        const long long tbase = btBase + (long long)nChunks * 768;
        for (int p = lane; p < tailPts; p += 64) {
            const float px = X[tbase + 3 * p + 0];
            const float py = X[tbase + 3 * p + 1];
            const float pz = X[tbase + 3 * p + 2];
            out[tbase + 3 * p + 0] = fmaf(R00, px, fmaf(R01, py, fmaf(R02, pz, Tx)));
            out[tbase + 3 * p + 1] = fmaf(R10, px, fmaf(R11, py, fmaf(R12, pz, Ty)));
            out[tbase + 3 * p + 2] = fmaf(R20, px, fmaf(R21, py, fmaf(R22, pz, Tz)));
        }
    }
}

extern "C" void kernel_launch(void* const* d_in, const int* in_sizes, int n_in,
                              void* d_out, int out_size, void* d_ws, size_t ws_size,
                              hipStream_t stream) {
    const float* X    = (const float*)d_in[0];
    const float* dofs = (const float*)d_in[1];
    float* out        = (float*)d_out;

    const int BT = in_sizes[1] / 6;            // 64*28 = 1792
    const int n3 = in_sizes[0] / BT;           // 4096*3 = 12288 floats per bt

    dim3 grid((unsigned)BT);                   // 1792 blocks = 7 per CU, one generation
    se3_apply_kernel<<<grid, 256, 0, stream>>>(X, dofs, out, n3);
}